// Round 2
// baseline (385.967 us; speedup 1.0000x reference)
//
#include <hip/hip_runtime.h>

// Problem: N=256, L=128, E=1024, H=16, D=64, S=2. FP32 tensors in memory.
// Only q[token_index], k[sidx], v[sidx] are needed -> 5 gathered skinny GEMMs
// + 32 tiny attention heads + one 256x1024 output projection.
//
// R2: FUSED single persistent kernel (256 blocks x 256 thr, 1 block/CU,
// co-resident by construction) with software grid barriers, replacing three
// dependent dispatches (saves 2 drain->dispatch gaps + kernel ramp tails).
//   phase 1: 640 32x32 MFMA wave-tiles spread over all 256 CUs
//   phase 2: attention; wave owns (h,s) + 4 consecutive q rows (K/V L1 reuse),
//            short8-vectorized QK dot, shfl-broadcast PV (no LDS, no syncs)
//   phase 3: outproj as 1024 16x16 MFMA wave-tiles (100% wave coverage)
// Barrier counters live in d_ws, zeroed per-iteration by a captured
// hipMemsetAsync (same op class as harness reset -> graph-capture-safe).
// Math identical to 359-us baseline: fp32 -> bf16-trunc frags -> MFMA f32 acc.

#define LL 128
#define EE 1024
#define HH 16
#define DD 64
#define SS 2
#define NBLK 256

typedef unsigned short u16;
typedef unsigned int   u32;
typedef __attribute__((ext_vector_type(8))) short short8;
typedef __attribute__((ext_vector_type(4))) float floatx4;

__device__ inline u32 pack_trunc(float lo, float hi) {
    return (__float_as_uint(hi) & 0xFFFF0000u) | (__float_as_uint(lo) >> 16);
}
__device__ inline u16 f2bf_rne(float f) {
    u32 u = __float_as_uint(f);
    return (u16)((u + 0x7FFFu + ((u >> 16) & 1u)) >> 16);
}
__device__ inline float bf2f(u16 x) { return __uint_as_float(((u32)x) << 16); }

// 8 consecutive fp32 at p (32B aligned) -> bf16 short8 fragment (truncate)
__device__ inline short8 frag_from_f32(const float* __restrict__ p) {
    floatx4 a = *(const floatx4*)p;
    floatx4 b = *(const floatx4*)(p + 4);
    union { short8 s; u32 w[4]; } r;
    r.w[0] = pack_trunc(a[0], a[1]);
    r.w[1] = pack_trunc(a[2], a[3]);
    r.w[2] = pack_trunc(b[0], b[1]);
    r.w[3] = pack_trunc(b[2], b[3]);
    return r.s;
}

__device__ inline int clamp_idx(int v) {            // defensive: keep in [0,256)
    return ((unsigned)v < 256u) ? v : (v & 255);
}

// Software grid barrier: 1 arrival per block; device-scope atomics (guide
// G12/m20: atomicAdd on global is device-scope) + __threadfence for cross-XCD
// L2 writeback/invalidate. Safe: grid(256 x 4 waves) <= co-residency capacity.
__device__ inline void grid_sync(u32* bar, u32 target) {
    __syncthreads();                       // all block writes drained (vmcnt0)
    if (threadIdx.x == 0) {
        __threadfence();                   // release: wb this XCD's L2
        atomicAdd(bar, 1u);
        while (atomicAdd(bar, 0u) < target)
            __builtin_amdgcn_s_sleep(8);
        __threadfence();                   // acquire: inv L1/L2 before reads
    }
    __syncthreads();
}

__global__ __launch_bounds__(256) void fused_attn(
    const float* __restrict__ values, const float* __restrict__ keys,
    const float* __restrict__ query,  const float* __restrict__ mask,
    const float* __restrict__ Wv, const float* __restrict__ bv,
    const float* __restrict__ Wk, const float* __restrict__ bk,
    const float* __restrict__ Wq, const float* __restrict__ bq,
    const float* __restrict__ Wo, const float* __restrict__ bo,
    const int* __restrict__ tok, const int* __restrict__ sidx,
    u16* __restrict__ q_sel, u16* __restrict__ k_sel, u16* __restrict__ v_sel,
    u16* __restrict__ wv, u32* __restrict__ bar, float* __restrict__ out)
{
    const int tid  = threadIdx.x;
    const int lane = tid & 63;
    const int w    = tid >> 6;
    const int b    = blockIdx.x;
    const int gid  = b * 4 + w;            // 0..1023 global wave id
    const size_t LE = (size_t)LL * EE;

    // ---------------- phase 1: gathered projections (5 x 128x1024) ---------
    // task t = w*NBLK + b spreads the 640 32x32 tiles across every CU.
    {
        const int t = w * NBLK + b;
        if (t < 640) {
            const int job  = t >> 7;           // 0..4
            const int rem  = t & 127;
            const int row0 = (rem >> 5) * 32;
            const int col0 = (rem & 31) * 32;
            const float *src, *W, *bias; u16* dst;
            if (job == 0)      { src = query  + (size_t)clamp_idx(tok[0])  * LE;
                                 W = Wq; bias = bq; dst = q_sel; }
            else if (job <= 2) { const int s = job - 1;
                                 src = keys   + (size_t)clamp_idx(sidx[s]) * LE;
                                 W = Wk; bias = bk; dst = k_sel + s * LE; }
            else               { const int s = job - 3;
                                 src = values + (size_t)clamp_idx(sidx[s]) * LE;
                                 W = Wv; bias = bv; dst = v_sel + s * LE; }

            const int lm = lane & 15, kq = (lane >> 4) * 8;
            floatx4 acc[2][2] = {};
            const float* a0p = src + (size_t)(row0 + lm) * EE + kq;
            const float* a1p = a0p + 16 * EE;
            const float* b0p = W   + (size_t)(col0 + lm) * EE + kq;
            const float* b1p = b0p + 16 * EE;

            short8 a0 = frag_from_f32(a0p), a1 = frag_from_f32(a1p);
            short8 b0 = frag_from_f32(b0p), b1 = frag_from_f32(b1p);
            for (int k0 = 32; k0 < EE; k0 += 32) {
                short8 na0 = frag_from_f32(a0p + k0);
                short8 na1 = frag_from_f32(a1p + k0);
                short8 nb0 = frag_from_f32(b0p + k0);
                short8 nb1 = frag_from_f32(b1p + k0);
                acc[0][0] = __builtin_amdgcn_mfma_f32_16x16x32_bf16(a0, b0, acc[0][0], 0, 0, 0);
                acc[0][1] = __builtin_amdgcn_mfma_f32_16x16x32_bf16(a0, b1, acc[0][1], 0, 0, 0);
                acc[1][0] = __builtin_amdgcn_mfma_f32_16x16x32_bf16(a1, b0, acc[1][0], 0, 0, 0);
                acc[1][1] = __builtin_amdgcn_mfma_f32_16x16x32_bf16(a1, b1, acc[1][1], 0, 0, 0);
                a0 = na0; a1 = na1; b0 = nb0; b1 = nb1;
            }
            acc[0][0] = __builtin_amdgcn_mfma_f32_16x16x32_bf16(a0, b0, acc[0][0], 0, 0, 0);
            acc[0][1] = __builtin_amdgcn_mfma_f32_16x16x32_bf16(a0, b1, acc[0][1], 0, 0, 0);
            acc[1][0] = __builtin_amdgcn_mfma_f32_16x16x32_bf16(a1, b0, acc[1][0], 0, 0, 0);
            acc[1][1] = __builtin_amdgcn_mfma_f32_16x16x32_bf16(a1, b1, acc[1][1], 0, 0, 0);

            const int rbase = (lane >> 4) * 4;
            #pragma unroll
            for (int i = 0; i < 2; ++i)
                #pragma unroll
                for (int j = 0; j < 2; ++j) {
                    const int ccol = col0 + j * 16 + lm;
                    const float bb = bias[ccol];
                    #pragma unroll
                    for (int r = 0; r < 4; ++r) {
                        const int crow = row0 + i * 16 + rbase + r;
                        dst[(size_t)crow * EE + ccol] = f2bf_rne(acc[i][j][r] + bb);
                    }
                }
        }
    }

    grid_sync(&bar[0], NBLK);

    // ---------------- phase 2: attention, wave = (h,s) x 4 q-rows ----------
    {
        const int hs = gid >> 5;             // 0..31
        const int s  = hs >> 4, h = hs & 15;
        const int q0 = (gid & 31) * 4;
        const u16* K0 = k_sel + ((size_t)s * LL + lane) * EE + h * DD;  // k=lane
        const u16* K1 = K0 + (size_t)64 * EE;                           // k=lane+64
        const u16* Vb = v_sel + (size_t)s * LL * EE + h * DD + lane;    // d=lane
        const float scale = 1.0f / 32.0f;

        for (int i = 0; i < 4; ++i) {
            const int q = q0 + i;
            const u16* Qr = q_sel + (size_t)q * EE + h * DD;

            float e0 = 0.f, e1 = 0.f;
            #pragma unroll
            for (int d8 = 0; d8 < 8; ++d8) {
                short8 qv  = *(const short8*)(Qr + d8 * 8);
                short8 k0v = *(const short8*)(K0 + d8 * 8);
                short8 k1v = *(const short8*)(K1 + d8 * 8);
                #pragma unroll
                for (int j = 0; j < 8; ++j) {
                    const float qf = bf2f((u16)qv[j]);
                    e0 += qf * bf2f((u16)k0v[j]);
                    e1 += qf * bf2f((u16)k1v[j]);
                }
            }

            // ref: energy = where(mask==0, -1e20, energy); softmax(energy/32)
            const float m0 = mask[q * LL + lane];
            const float m1 = mask[q * LL + lane + 64];
            e0 = (m0 == 0.f ? -1.0e20f : e0) * scale;
            e1 = (m1 == 0.f ? -1.0e20f : e1) * scale;

            float m = fmaxf(e0, e1);
            #pragma unroll
            for (int off = 32; off >= 1; off >>= 1) m = fmaxf(m, __shfl_xor(m, off));
            float p0 = __expf(e0 - m), p1 = __expf(e1 - m);
            float sum = p0 + p1;
            #pragma unroll
            for (int off = 32; off >= 1; off >>= 1) sum += __shfl_xor(sum, off);
            const float inv = 1.0f / sum;
            p0 *= inv; p1 *= inv;

            // PV via shfl broadcast (lane = d); no LDS, no barriers
            float acc0 = 0.f, acc1 = 0.f;
            #pragma unroll 8
            for (int k = 0; k < 64; ++k) {
                acc0 += __shfl(p0, k) * bf2f(Vb[(size_t)k * EE]);
                acc1 += __shfl(p1, k) * bf2f(Vb[(size_t)(k + 64) * EE]);
            }
            wv[((size_t)s * LL + q) * EE + h * DD + lane] = f2bf_rne(acc0 + acc1);
        }
    }

    grid_sync(&bar[1], NBLK);

    // ---------------- phase 3: out = wv @ Wo^T + bo (1024 16x16 tiles) -----
    {
        const int row0 = (gid >> 6) * 16;    // 16 row-tiles
        const int col0 = (gid & 63) * 16;    // 64 col-tiles
        const int lm = lane & 15, kq = (lane >> 4) * 8;

        floatx4 acc = {0.f, 0.f, 0.f, 0.f};
        const u16*   ap = wv + (size_t)(row0 + lm) * EE + kq;
        const float* bp = Wo + (size_t)(col0 + lm) * EE + kq;

        short8 a = *(const short8*)ap;
        short8 bf = frag_from_f32(bp);
        for (int k0 = 32; k0 < EE; k0 += 32) {
            short8 na = *(const short8*)(ap + k0);
            short8 nb = frag_from_f32(bp + k0);
            acc = __builtin_amdgcn_mfma_f32_16x16x32_bf16(a, bf, acc, 0, 0, 0);
            a = na; bf = nb;
        }
        acc = __builtin_amdgcn_mfma_f32_16x16x32_bf16(a, bf, acc, 0, 0, 0);

        const int rbase = (lane >> 4) * 4;
        const int ccol  = col0 + lm;
        const float bb  = bo[ccol];
        #pragma unroll
        for (int r = 0; r < 4; ++r)
            out[(size_t)(row0 + rbase + r) * EE + ccol] = acc[r] + bb;
    }
}

extern "C" void kernel_launch(void* const* d_in, const int* in_sizes, int n_in,
                              void* d_out, int out_size, void* d_ws, size_t ws_size,
                              hipStream_t stream) {
    const float* values = (const float*)d_in[0];
    const float* keys   = (const float*)d_in[1];
    const float* query  = (const float*)d_in[2];
    const float* mask   = (const float*)d_in[3];
    const float* Wv     = (const float*)d_in[4];
    const float* bv     = (const float*)d_in[5];
    const float* Wk     = (const float*)d_in[6];
    const float* bk     = (const float*)d_in[7];
    const float* Wq     = (const float*)d_in[8];
    const float* bq     = (const float*)d_in[9];
    const float* Wo     = (const float*)d_in[10];
    const float* bo     = (const float*)d_in[11];
    const int*   tok    = (const int*)d_in[12];
    const int*   sidx   = (const int*)d_in[13];
    float* out = (float*)d_out;

    const size_t LE = (size_t)LL * EE;      // 131072 elems
    u16* q_sel = (u16*)d_ws;                // L*E        bf16
    u16* k_sel = q_sel + LE;                // S*L*E
    u16* v_sel = k_sel + SS * LE;           // S*L*E
    u16* wv    = v_sel + SS * LE;           // S*L*E      (1.75 MB used)
    u32* bar   = (u32*)((char*)d_ws + (1792u * 1024u));  // just past wv, 1KB-aligned

    // zero barrier counters each iteration (captured into the graph)
    hipMemsetAsync(bar, 0, 64, stream);

    fused_attn<<<dim3(NBLK), dim3(256), 0, stream>>>(
        values, keys, query, mask, Wv, bv, Wk, bk, Wq, bq, Wo, bo,
        tok, sidx, q_sel, k_sel, v_sel, wv, bar, out);
}